// Round 2
// baseline (150.628 us; speedup 1.0000x reference)
//
#include <hip/hip_runtime.h>
#include <hip/hip_bf16.h>

// Prototypical nets head:
//   s_emb [64,16,2048] f32, q_emb [64,512,2048] f32
//   out = concat(log_p_y [64,512,64] f32, ce_loss f32, acc f32)

typedef __attribute__((ext_vector_type(8))) short bf16x8;
typedef __attribute__((ext_vector_type(4))) float f32x4;

#define N_WAY 64
#define N_SHOT 16
#define N_QUERY 512
#define DIM 2048
#define N_ROWS (N_WAY * N_QUERY)      // 32768
#define OUT_LOGP (N_ROWS * N_WAY)     // 2097152
#define KSLICES 8
#define KS (DIM / KSLICES)            // 256
#define KSPLIT 4
#define KSEG (DIM / KSPLIT)           // 512

static __device__ __forceinline__ short f2bf(float x) {
  union { __hip_bfloat16 b; short s; } u;
  u.b = __float2bfloat16(x);
  return u.s;
}

// ---------------------------------------------------------------------------
// Kernel 1: per-(way, k-slice) prototype mean -> bf16 proto table + partial sumsq
__global__ void proto_part(const float* __restrict__ s_emb,
                           __hip_bfloat16* __restrict__ proto,
                           float* __restrict__ c_part) {
  int b = blockIdx.x;          // 0..511
  int m = b >> 3;              // way 0..63
  int ks = b & 7;              // k-slice 0..7
  int t = threadIdx.x;         // 0..255
  int k = ks * KS + t;

  const float* base = s_emb + ((size_t)m * N_SHOT) * DIM + k;
  float s = 0.f;
#pragma unroll
  for (int j = 0; j < N_SHOT; ++j) s += base[(size_t)j * DIM];
  float p = s * (1.0f / N_SHOT);
  proto[m * DIM + k] = __float2bfloat16(p);

  float sq = p * p;
#pragma unroll
  for (int off = 1; off < 64; off <<= 1) sq += __shfl_xor(sq, off);

  __shared__ float red[4];
  int lane = t & 63, w = t >> 6;
  if (lane == 0) red[w] = sq;
  __syncthreads();
  if (t == 0) {
    c_part[m * KSLICES + ks] = red[0] + red[1] + red[2] + red[3];
  }
}

// ---------------------------------------------------------------------------
// Kernel 2: finalize c[m] = |p_m|^2 / D, zero the scalar output slots
__global__ void proto_fin(const float* __restrict__ c_part,
                          float* __restrict__ c,
                          float* __restrict__ scalars) {
  int t = threadIdx.x; // 64 threads
  if (t < N_WAY) {
    float s = 0.f;
#pragma unroll
    for (int i = 0; i < KSLICES; ++i) s += c_part[t * KSLICES + i];
    c[t] = s * (1.0f / DIM);
  }
  if (t < 2) scalars[t] = 0.f;
}

// ---------------------------------------------------------------------------
// Kernel 3: main. One block (4 waves) per 16-row tile; wave w covers
// dims [w*512, w*512+512); LDS-reduce partials; wave 0 does the epilogue.
//   s_m = (2 q.p_m - |p_m|^2)/D ; log_p = s - lse(s) (sq_q cancels in softmax)
__launch_bounds__(256, 8)
__global__ void dist_kernel(const float* __restrict__ q,
                            const __hip_bfloat16* __restrict__ proto,
                            const float* __restrict__ c,
                            float* __restrict__ out,
                            float* __restrict__ scalars) {
  int tid = threadIdx.x;
  int w = tid >> 6;              // wave in block, 0..3 -> K segment
  int lane = tid & 63;
  int l15 = lane & 15;
  int g = lane >> 4;
  int rowbase = blockIdx.x * 16;
  int k0 = w * KSEG;

  const float* qp = q + (size_t)(rowbase + l15) * DIM + k0 + g * 8;
  const short* pp = (const short*)proto + l15 * DIM + k0 + g * 8;

  f32x4 acc[4];
#pragma unroll
  for (int ct = 0; ct < 4; ++ct) acc[ct] = (f32x4){0.f, 0.f, 0.f, 0.f};

#pragma unroll 2
  for (int k = 0; k < KSEG; k += 32) {
    float4 a0 = *reinterpret_cast<const float4*>(qp + k);
    float4 a1 = *reinterpret_cast<const float4*>(qp + k + 4);
    bf16x8 af;
    af[0] = f2bf(a0.x); af[1] = f2bf(a0.y); af[2] = f2bf(a0.z); af[3] = f2bf(a0.w);
    af[4] = f2bf(a1.x); af[5] = f2bf(a1.y); af[6] = f2bf(a1.z); af[7] = f2bf(a1.w);
#pragma unroll
    for (int ct = 0; ct < 4; ++ct) {
      bf16x8 bf = *reinterpret_cast<const bf16x8*>(pp + ct * (16 * DIM) + k);
      acc[ct] = __builtin_amdgcn_mfma_f32_16x16x32_bf16(af, bf, acc[ct], 0, 0, 0);
    }
  }

  // cross-wave reduction of partial accumulators (padded to dodge conflicts)
  __shared__ float red[KSPLIT - 1][64][20];
  if (w != 0) {
#pragma unroll
    for (int ct = 0; ct < 4; ++ct)
      *reinterpret_cast<f32x4*>(&red[w - 1][lane][ct * 4]) = acc[ct];
  }
  __syncthreads();
  if (w != 0) return;

#pragma unroll
  for (int j = 0; j < KSPLIT - 1; ++j)
#pragma unroll
    for (int ct = 0; ct < 4; ++ct)
      acc[ct] += *reinterpret_cast<const f32x4*>(&red[j][lane][ct * 4]);

  // c for this lane's 4 columns (col = ct*16 + l15)
  float cc[4];
#pragma unroll
  for (int ct = 0; ct < 4; ++ct) cc[ct] = c[ct * 16 + l15];

  const float scale = 2.0f / (float)DIM;
  float ce_part = 0.f;
  float acc_part = 0.f;

#pragma unroll
  for (int r = 0; r < 4; ++r) {
    int row = rowbase + g * 4 + r;
    int wy = row >> 9;           // true class = row / N_QUERY

    float s0 = acc[0][r] * scale - cc[0];
    float s1 = acc[1][r] * scale - cc[1];
    float s2 = acc[2][r] * scale - cc[2];
    float s3 = acc[3][r] * scale - cc[3];

    // row max across 4 local cols + 16 lanes of this group
    float mx = fmaxf(fmaxf(s0, s1), fmaxf(s2, s3));
#pragma unroll
    for (int off = 1; off < 16; off <<= 1) mx = fmaxf(mx, __shfl_xor(mx, off));

    float e = __expf(s0 - mx) + __expf(s1 - mx) + __expf(s2 - mx) + __expf(s3 - mx);
#pragma unroll
    for (int off = 1; off < 16; off <<= 1) e += __shfl_xor(e, off);
    float lse = mx + __logf(e);

    size_t ob = (size_t)row * N_WAY + l15;
    out[ob]      = s0 - lse;
    out[ob + 16] = s1 - lse;
    out[ob + 32] = s2 - lse;
    out[ob + 48] = s3 - lse;

    // CE: -log_p[row, wy] = lse - s_wy ; col ct*16+l15 == wy
    if (l15 == (wy & 15)) {
      int ct = wy >> 4;
      float sw = (ct == 0) ? s0 : (ct == 1) ? s1 : (ct == 2) ? s2 : s3;
      ce_part += lse - sw;
    }

    // argmax with first-occurrence tie-break
    float bv = s0; int bi = l15;
    if (s1 > bv) { bv = s1; bi = l15 + 16; }
    if (s2 > bv) { bv = s2; bi = l15 + 32; }
    if (s3 > bv) { bv = s3; bi = l15 + 48; }
#pragma unroll
    for (int off = 1; off < 16; off <<= 1) {
      float ov = __shfl_xor(bv, off);
      int oi = __shfl_xor(bi, off);
      if (ov > bv || (ov == bv && oi < bi)) { bv = ov; bi = oi; }
    }
    if (l15 == 0) acc_part += (bi == wy) ? 1.0f : 0.0f;
  }

  // full-wave reduce of scalar partials, one atomic pair per wave
#pragma unroll
  for (int off = 1; off < 64; off <<= 1) {
    ce_part += __shfl_xor(ce_part, off);
    acc_part += __shfl_xor(acc_part, off);
  }
  if (lane == 0) {
    atomicAdd(&scalars[0], ce_part * (1.0f / N_ROWS));
    atomicAdd(&scalars[1], acc_part * (1.0f / N_ROWS));
  }
}

// ---------------------------------------------------------------------------
extern "C" void kernel_launch(void* const* d_in, const int* in_sizes, int n_in,
                              void* d_out, int out_size, void* d_ws, size_t ws_size,
                              hipStream_t stream) {
  const float* s_emb = (const float*)d_in[0];
  const float* q_emb = (const float*)d_in[1];
  float* out = (float*)d_out;
  char* ws = (char*)d_ws;

  __hip_bfloat16* proto = (__hip_bfloat16*)ws;                 // 256 KB
  float* c_part = (float*)(ws + 256 * 1024);                   // 2 KB
  float* c = (float*)(ws + 256 * 1024 + 4096);                 // 256 B
  float* scalars = out + OUT_LOGP;

  hipLaunchKernelGGL(proto_part, dim3(512), dim3(256), 0, stream, s_emb, proto, c_part);
  hipLaunchKernelGGL(proto_fin, dim3(1), dim3(64), 0, stream, c_part, c, scalars);
  hipLaunchKernelGGL(dist_kernel, dim3(N_ROWS / 16), dim3(256), 0, stream,
                     q_emb, proto, c, out, scalars);
}

// Round 3
// 127.803 us; speedup vs baseline: 1.1786x; 1.1786x over previous
//
#include <hip/hip_runtime.h>
#include <hip/hip_bf16.h>

// Prototypical nets head:
//   s_emb [64,16,2048] f32, q_emb [64,512,2048] f32
//   out = concat(log_p_y [64,512,64] f32, ce_loss f32, acc f32)

typedef __attribute__((ext_vector_type(8))) short bf16x8;
typedef __attribute__((ext_vector_type(4))) float f32x4;

#define N_WAY 64
#define N_SHOT 16
#define N_QUERY 512
#define DIM 2048
#define N_ROWS (N_WAY * N_QUERY)      // 32768
#define OUT_LOGP (N_ROWS * N_WAY)     // 2097152
#define KSLICES 8
#define KS (DIM / KSLICES)            // 256
#define KSPLIT 4
#define KSEG (DIM / KSPLIT)           // 512

static __device__ __forceinline__ short f2bf(float x) {
  union { __hip_bfloat16 b; short s; } u;
  u.b = __float2bfloat16(x);
  return u.s;
}

// ---------------------------------------------------------------------------
// Kernel 1: per-(way, k-slice) prototype mean -> bf16 proto table + partial sumsq
__global__ void proto_part(const float* __restrict__ s_emb,
                           __hip_bfloat16* __restrict__ proto,
                           float* __restrict__ c_part) {
  int b = blockIdx.x;          // 0..511
  int m = b >> 3;              // way 0..63
  int ks = b & 7;              // k-slice 0..7
  int t = threadIdx.x;         // 0..255
  int k = ks * KS + t;

  const float* base = s_emb + ((size_t)m * N_SHOT) * DIM + k;
  float s = 0.f;
#pragma unroll
  for (int j = 0; j < N_SHOT; ++j) s += base[(size_t)j * DIM];
  float p = s * (1.0f / N_SHOT);
  proto[m * DIM + k] = __float2bfloat16(p);

  float sq = p * p;
#pragma unroll
  for (int off = 1; off < 64; off <<= 1) sq += __shfl_xor(sq, off);

  __shared__ float red[4];
  int lane = t & 63, w = t >> 6;
  if (lane == 0) red[w] = sq;
  __syncthreads();
  if (t == 0) {
    c_part[m * KSLICES + ks] = red[0] + red[1] + red[2] + red[3];
  }
}

// ---------------------------------------------------------------------------
// Kernel 2: finalize c[m] = |p_m|^2 / D, zero the scalar output slots
__global__ void proto_fin(const float* __restrict__ c_part,
                          float* __restrict__ c,
                          float* __restrict__ scalars) {
  int t = threadIdx.x; // 64 threads
  if (t < N_WAY) {
    float s = 0.f;
#pragma unroll
    for (int i = 0; i < KSLICES; ++i) s += c_part[t * KSLICES + i];
    c[t] = s * (1.0f / DIM);
  }
  if (t < 2) scalars[t] = 0.f;
}

// ---------------------------------------------------------------------------
// Kernel 3: main. One block (4 waves) per 16-row tile; wave w covers
// dims [w*512, w*512+512); LDS-reduce partials; wave 0 does the epilogue.
// Explicit 1-deep software pipeline: prefetch next k-step's q + proto
// fragments before the current MFMAs so loads stay in flight (counted vmcnt).
//   s_m = (2 q.p_m - |p_m|^2)/D ; log_p = s - lse(s) (sq_q cancels in softmax)
__launch_bounds__(256, 4)
__global__ void dist_kernel(const float* __restrict__ q,
                            const __hip_bfloat16* __restrict__ proto,
                            const float* __restrict__ c,
                            float* __restrict__ out,
                            float* __restrict__ scalars) {
  int tid = threadIdx.x;
  int w = tid >> 6;              // wave in block, 0..3 -> K segment
  int lane = tid & 63;
  int l15 = lane & 15;
  int g = lane >> 4;
  int rowbase = blockIdx.x * 16;
  int k0 = w * KSEG;

  const float* qp = q + (size_t)(rowbase + l15) * DIM + k0 + g * 8;
  const short* pp = (const short*)proto + l15 * DIM + k0 + g * 8;

  f32x4 acc[4];
#pragma unroll
  for (int ct = 0; ct < 4; ++ct) acc[ct] = (f32x4){0.f, 0.f, 0.f, 0.f};

  // prime the pipeline
  float4 a0 = *reinterpret_cast<const float4*>(qp);
  float4 a1 = *reinterpret_cast<const float4*>(qp + 4);
  bf16x8 bb[4];
#pragma unroll
  for (int ct = 0; ct < 4; ++ct)
    bb[ct] = *reinterpret_cast<const bf16x8*>(pp + ct * (16 * DIM));

#pragma unroll 2
  for (int k = 0; k < KSEG; k += 32) {
    int kn = (k + 32 < KSEG) ? (k + 32) : 0;   // clamped: last prefetch harmless
    float4 na0 = *reinterpret_cast<const float4*>(qp + kn);
    float4 na1 = *reinterpret_cast<const float4*>(qp + kn + 4);
    bf16x8 nb[4];
#pragma unroll
    for (int ct = 0; ct < 4; ++ct)
      nb[ct] = *reinterpret_cast<const bf16x8*>(pp + ct * (16 * DIM) + kn);

    bf16x8 af;
    af[0] = f2bf(a0.x); af[1] = f2bf(a0.y); af[2] = f2bf(a0.z); af[3] = f2bf(a0.w);
    af[4] = f2bf(a1.x); af[5] = f2bf(a1.y); af[6] = f2bf(a1.z); af[7] = f2bf(a1.w);
#pragma unroll
    for (int ct = 0; ct < 4; ++ct)
      acc[ct] = __builtin_amdgcn_mfma_f32_16x16x32_bf16(af, bb[ct], acc[ct], 0, 0, 0);

    a0 = na0; a1 = na1;
#pragma unroll
    for (int ct = 0; ct < 4; ++ct) bb[ct] = nb[ct];
  }

  // cross-wave reduction of partial accumulators (padded to dodge conflicts)
  __shared__ float red[KSPLIT - 1][64][20];
  if (w != 0) {
#pragma unroll
    for (int ct = 0; ct < 4; ++ct)
      *reinterpret_cast<f32x4*>(&red[w - 1][lane][ct * 4]) = acc[ct];
  }
  __syncthreads();
  if (w != 0) return;

#pragma unroll
  for (int j = 0; j < KSPLIT - 1; ++j)
#pragma unroll
    for (int ct = 0; ct < 4; ++ct)
      acc[ct] += *reinterpret_cast<const f32x4*>(&red[j][lane][ct * 4]);

  // c for this lane's 4 columns (col = ct*16 + l15)
  float cc[4];
#pragma unroll
  for (int ct = 0; ct < 4; ++ct) cc[ct] = c[ct * 16 + l15];

  const float scale = 2.0f / (float)DIM;
  float ce_part = 0.f;
  float acc_part = 0.f;

#pragma unroll
  for (int r = 0; r < 4; ++r) {
    int row = rowbase + g * 4 + r;
    int wy = row >> 9;           // true class = row / N_QUERY

    float s0 = acc[0][r] * scale - cc[0];
    float s1 = acc[1][r] * scale - cc[1];
    float s2 = acc[2][r] * scale - cc[2];
    float s3 = acc[3][r] * scale - cc[3];

    // row max across 4 local cols + 16 lanes of this group
    float mx = fmaxf(fmaxf(s0, s1), fmaxf(s2, s3));
#pragma unroll
    for (int off = 1; off < 16; off <<= 1) mx = fmaxf(mx, __shfl_xor(mx, off));

    float e = __expf(s0 - mx) + __expf(s1 - mx) + __expf(s2 - mx) + __expf(s3 - mx);
#pragma unroll
    for (int off = 1; off < 16; off <<= 1) e += __shfl_xor(e, off);
    float lse = mx + __logf(e);

    size_t ob = (size_t)row * N_WAY + l15;
    out[ob]      = s0 - lse;
    out[ob + 16] = s1 - lse;
    out[ob + 32] = s2 - lse;
    out[ob + 48] = s3 - lse;

    // CE: -log_p[row, wy] = lse - s_wy ; col ct*16+l15 == wy
    if (l15 == (wy & 15)) {
      int ct = wy >> 4;
      float sw = (ct == 0) ? s0 : (ct == 1) ? s1 : (ct == 2) ? s2 : s3;
      ce_part += lse - sw;
    }

    // argmax with first-occurrence tie-break
    float bv = s0; int bi = l15;
    if (s1 > bv) { bv = s1; bi = l15 + 16; }
    if (s2 > bv) { bv = s2; bi = l15 + 32; }
    if (s3 > bv) { bv = s3; bi = l15 + 48; }
#pragma unroll
    for (int off = 1; off < 16; off <<= 1) {
      float ov = __shfl_xor(bv, off);
      int oi = __shfl_xor(bi, off);
      if (ov > bv || (ov == bv && oi < bi)) { bv = ov; bi = oi; }
    }
    if (l15 == 0) acc_part += (bi == wy) ? 1.0f : 0.0f;
  }

  // full-wave reduce of scalar partials, one atomic pair per wave
#pragma unroll
  for (int off = 1; off < 64; off <<= 1) {
    ce_part += __shfl_xor(ce_part, off);
    acc_part += __shfl_xor(acc_part, off);
  }
  if (lane == 0) {
    atomicAdd(&scalars[0], ce_part * (1.0f / N_ROWS));
    atomicAdd(&scalars[1], acc_part * (1.0f / N_ROWS));
  }
}

// ---------------------------------------------------------------------------
extern "C" void kernel_launch(void* const* d_in, const int* in_sizes, int n_in,
                              void* d_out, int out_size, void* d_ws, size_t ws_size,
                              hipStream_t stream) {
  const float* s_emb = (const float*)d_in[0];
  const float* q_emb = (const float*)d_in[1];
  float* out = (float*)d_out;
  char* ws = (char*)d_ws;

  __hip_bfloat16* proto = (__hip_bfloat16*)ws;                 // 256 KB
  float* c_part = (float*)(ws + 256 * 1024);                   // 2 KB
  float* c = (float*)(ws + 256 * 1024 + 4096);                 // 256 B
  float* scalars = out + OUT_LOGP;

  hipLaunchKernelGGL(proto_part, dim3(512), dim3(256), 0, stream, s_emb, proto, c_part);
  hipLaunchKernelGGL(proto_fin, dim3(1), dim3(64), 0, stream, c_part, c, scalars);
  hipLaunchKernelGGL(dist_kernel, dim3(N_ROWS / 16), dim3(256), 0, stream,
                     q_emb, proto, c, out, scalars);
}

// Round 4
// 102.606 us; speedup vs baseline: 1.4680x; 1.2456x over previous
//
#include <hip/hip_runtime.h>
#include <hip/hip_bf16.h>

// Prototypical nets head:
//   s_emb [64,16,2048] f32, q_emb [64,512,2048] f32
//   out = concat(log_p_y [64,512,64] f32, ce_loss f32, acc f32)
//
// dist_kernel: block = 64 query rows, 4 waves (16 rows each), full K per wave.
// Per 64-dim chunk: coalesced global->reg->LDS staging (q cvt'd to bf16),
// XOR-swizzled granule layout for conflict-free ds_read_b128 fragments,
// double-buffered LDS, one barrier per chunk, next-chunk loads in flight
// during compute. This replaces 16-way divergent direct fragment loads
// (the round-1..3 limiter: ~16 cache-line transactions per load instr).

typedef __attribute__((ext_vector_type(8))) short bf16x8;
typedef __attribute__((ext_vector_type(4))) short s16x4;
typedef __attribute__((ext_vector_type(4))) float f32x4;

#define N_WAY 64
#define N_SHOT 16
#define N_QUERY 512
#define DIM 2048
#define N_ROWS (N_WAY * N_QUERY)      // 32768
#define OUT_LOGP (N_ROWS * N_WAY)     // 2097152
#define KSLICES 8
#define KS (DIM / KSLICES)            // 256
#define KC 64                         // dims per staged chunk
#define NC (DIM / KC)                 // 32 chunks
#define ROWS_BLK 64                   // rows per block

static __device__ __forceinline__ short f2bf(float x) {
  union { __hip_bfloat16 b; short s; } u;
  u.b = __float2bfloat16(x);
  return u.s;
}

// ---------------------------------------------------------------------------
// Kernel 1: per-(way, k-slice) prototype mean -> bf16 proto table + partial sumsq
__global__ void proto_part(const float* __restrict__ s_emb,
                           __hip_bfloat16* __restrict__ proto,
                           float* __restrict__ c_part) {
  int b = blockIdx.x;          // 0..511
  int m = b >> 3;              // way 0..63
  int ks = b & 7;              // k-slice 0..7
  int t = threadIdx.x;         // 0..255
  int k = ks * KS + t;

  const float* base = s_emb + ((size_t)m * N_SHOT) * DIM + k;
  float s = 0.f;
#pragma unroll
  for (int j = 0; j < N_SHOT; ++j) s += base[(size_t)j * DIM];
  float p = s * (1.0f / N_SHOT);
  proto[m * DIM + k] = __float2bfloat16(p);

  float sq = p * p;
#pragma unroll
  for (int off = 1; off < 64; off <<= 1) sq += __shfl_xor(sq, off);

  __shared__ float red[4];
  int lane = t & 63, w = t >> 6;
  if (lane == 0) red[w] = sq;
  __syncthreads();
  if (t == 0) {
    c_part[m * KSLICES + ks] = red[0] + red[1] + red[2] + red[3];
  }
}

// ---------------------------------------------------------------------------
// Kernel 2: finalize c[m] = |p_m|^2 / D, zero the scalar output slots
__global__ void proto_fin(const float* __restrict__ c_part,
                          float* __restrict__ c,
                          float* __restrict__ scalars) {
  int t = threadIdx.x; // 64 threads
  if (t < N_WAY) {
    float s = 0.f;
#pragma unroll
    for (int i = 0; i < KSLICES; ++i) s += c_part[t * KSLICES + i];
    c[t] = s * (1.0f / DIM);
  }
  if (t < 2) scalars[t] = 0.f;
}

// ---------------------------------------------------------------------------
// Kernel 3: main.
//   s_m = (2 q.p_m - |p_m|^2)/D ; log_p = s - lse(s) (sq_q cancels in softmax)
// LDS layout per buffer (16 KB): q bf16 [64 rows][64 dims] at 0, proto bf16
// [64 ways][64 dims] at 8192. Element (row,d) lives at byte
//   row*128 + ((d>>3 ^ (row&7))<<4) + (d&7)*2
// so a 16-B granule holds dims [8*gc8, 8*gc8+8) of one row, XOR-spread over
// the 8 slots of the 128-B row -> ds_read_b128 fragment reads are 2-way max
// per 16-lane phase (free).
__launch_bounds__(256, 4)
__global__ void dist_kernel(const float* __restrict__ q,
                            const __hip_bfloat16* __restrict__ proto,
                            const float* __restrict__ c,
                            float* __restrict__ out,
                            float* __restrict__ scalars) {
  __shared__ __align__(16) char lds[2][16384];

  int tid = threadIdx.x;
  int wv = tid >> 6;
  int lane = tid & 63;
  int l15 = lane & 15;
  int g = lane >> 4;
  int row0 = blockIdx.x * ROWS_BLK;

  const short* pt = (const short*)proto;

  f32x4 acc[4];
#pragma unroll
  for (int ct = 0; ct < 4; ++ct) acc[ct] = (f32x4){0.f, 0.f, 0.f, 0.f};

  float4 qs[4];      // staged q chunk (this thread's 16 floats)
  bf16x8 pr[2];      // staged proto chunk (this thread's 16 bf16)

  // coalesced global loads for chunk at dim offset kc
  auto load_chunk = [&](int kc) {
#pragma unroll
    for (int r = 0; r < 4; ++r) {
      int idx = (r << 8) + tid;          // 0..1023
      int row = idx >> 4;                // 4 rows per wave-instr, 256 B each
      int d4 = (idx & 15) << 2;
      qs[r] = *reinterpret_cast<const float4*>(
          q + (size_t)(row0 + row) * DIM + kc + d4);
    }
#pragma unroll
    for (int r = 0; r < 2; ++r) {
      int idx = (r << 8) + tid;          // 0..511
      int way = idx >> 3;                // 8 ways per wave-instr, 128 B each
      int g8 = idx & 7;
      pr[r] = *reinterpret_cast<const bf16x8*>(pt + way * DIM + kc + (g8 << 3));
    }
  };

  auto write_chunk = [&](char* buf) {
#pragma unroll
    for (int r = 0; r < 4; ++r) {
      int idx = (r << 8) + tid;
      int row = idx >> 4;
      int d4 = (idx & 15) << 2;
      int byte = (row << 7) + ((((d4 >> 3) ^ (row & 7))) << 4) + ((d4 & 7) << 1);
      s16x4 h;
      h[0] = f2bf(qs[r].x); h[1] = f2bf(qs[r].y);
      h[2] = f2bf(qs[r].z); h[3] = f2bf(qs[r].w);
      *reinterpret_cast<s16x4*>(buf + byte) = h;   // ds_write_b64, conflict-free
    }
#pragma unroll
    for (int r = 0; r < 2; ++r) {
      int idx = (r << 8) + tid;
      int way = idx >> 3;
      int g8 = idx & 7;
      int byte = 8192 + (way << 7) + ((g8 ^ (way & 7)) << 4);
      *reinterpret_cast<bf16x8*>(buf + byte) = pr[r]; // ds_write_b128
    }
  };

  int arow = (wv << 4) + l15;            // this lane's q row within block
  int aoff = arow << 7;
  auto compute_chunk = [&](const char* buf) {
#pragma unroll
    for (int ks = 0; ks < 2; ++ks) {
      bf16x8 af = *reinterpret_cast<const bf16x8*>(
          buf + aoff + ((((ks << 2) + g) ^ (arow & 7)) << 4));
#pragma unroll
      for (int ct = 0; ct < 4; ++ct) {
        int way = (ct << 4) + l15;
        bf16x8 bv = *reinterpret_cast<const bf16x8*>(
            buf + 8192 + (way << 7) + ((((ks << 2) + g) ^ (way & 7)) << 4));
        acc[ct] = __builtin_amdgcn_mfma_f32_16x16x32_bf16(af, bv, acc[ct], 0, 0, 0);
      }
    }
  };

  load_chunk(0);
#pragma unroll 2
  for (int cix = 0; cix < NC; ++cix) {
    char* buf = lds[cix & 1];
    write_chunk(buf);                       // waits on chunk cix's loads
    if (cix + 1 < NC) load_chunk((cix + 1) * KC);  // in flight during compute
    __syncthreads();                        // one barrier per chunk (dbuf-safe)
    compute_chunk(buf);
  }

  // ---- epilogue: each wave finishes its own 16 rows ----
  float cc[4];
#pragma unroll
  for (int ct = 0; ct < 4; ++ct) cc[ct] = c[ct * 16 + l15];

  const float scale = 2.0f / (float)DIM;
  float ce_part = 0.f;
  float acc_part = 0.f;
  int rowbase = row0 + (wv << 4);

#pragma unroll
  for (int r = 0; r < 4; ++r) {
    int row = rowbase + g * 4 + r;
    int wy = row >> 9;           // true class = row / N_QUERY

    float s0 = acc[0][r] * scale - cc[0];
    float s1 = acc[1][r] * scale - cc[1];
    float s2 = acc[2][r] * scale - cc[2];
    float s3 = acc[3][r] * scale - cc[3];

    // row max across 4 local cols + 16 lanes of this group
    float mx = fmaxf(fmaxf(s0, s1), fmaxf(s2, s3));
#pragma unroll
    for (int off = 1; off < 16; off <<= 1) mx = fmaxf(mx, __shfl_xor(mx, off));

    float e = __expf(s0 - mx) + __expf(s1 - mx) + __expf(s2 - mx) + __expf(s3 - mx);
#pragma unroll
    for (int off = 1; off < 16; off <<= 1) e += __shfl_xor(e, off);
    float lse = mx + __logf(e);

    size_t ob = (size_t)row * N_WAY + l15;
    out[ob]      = s0 - lse;
    out[ob + 16] = s1 - lse;
    out[ob + 32] = s2 - lse;
    out[ob + 48] = s3 - lse;

    // CE: -log_p[row, wy] = lse - s_wy ; col ct*16+l15 == wy
    if (l15 == (wy & 15)) {
      int ct = wy >> 4;
      float sw = (ct == 0) ? s0 : (ct == 1) ? s1 : (ct == 2) ? s2 : s3;
      ce_part += lse - sw;
    }

    // argmax with first-occurrence tie-break
    float bv = s0; int bi = l15;
    if (s1 > bv) { bv = s1; bi = l15 + 16; }
    if (s2 > bv) { bv = s2; bi = l15 + 32; }
    if (s3 > bv) { bv = s3; bi = l15 + 48; }
#pragma unroll
    for (int off = 1; off < 16; off <<= 1) {
      float ov = __shfl_xor(bv, off);
      int oi = __shfl_xor(bi, off);
      if (ov > bv || (ov == bv && oi < bi)) { bv = ov; bi = oi; }
    }
    if (l15 == 0) acc_part += (bi == wy) ? 1.0f : 0.0f;
  }

  // full-wave reduce of scalar partials, one atomic pair per wave
#pragma unroll
  for (int off = 1; off < 64; off <<= 1) {
    ce_part += __shfl_xor(ce_part, off);
    acc_part += __shfl_xor(acc_part, off);
  }
  if (lane == 0) {
    atomicAdd(&scalars[0], ce_part * (1.0f / N_ROWS));
    atomicAdd(&scalars[1], acc_part * (1.0f / N_ROWS));
  }
}

// ---------------------------------------------------------------------------
extern "C" void kernel_launch(void* const* d_in, const int* in_sizes, int n_in,
                              void* d_out, int out_size, void* d_ws, size_t ws_size,
                              hipStream_t stream) {
  const float* s_emb = (const float*)d_in[0];
  const float* q_emb = (const float*)d_in[1];
  float* out = (float*)d_out;
  char* ws = (char*)d_ws;

  __hip_bfloat16* proto = (__hip_bfloat16*)ws;                 // 256 KB
  float* c_part = (float*)(ws + 256 * 1024);                   // 2 KB
  float* c = (float*)(ws + 256 * 1024 + 4096);                 // 256 B
  float* scalars = out + OUT_LOGP;

  hipLaunchKernelGGL(proto_part, dim3(512), dim3(256), 0, stream, s_emb, proto, c_part);
  hipLaunchKernelGGL(proto_fin, dim3(1), dim3(64), 0, stream, c_part, c, scalars);
  hipLaunchKernelGGL(dist_kernel, dim3(N_ROWS / ROWS_BLK), dim3(256), 0, stream,
                     q_emb, proto, c, out, scalars);
}

// Round 5
// 101.936 us; speedup vs baseline: 1.4777x; 1.0066x over previous
//
#include <hip/hip_runtime.h>
#include <hip/hip_bf16.h>

// Prototypical nets head:
//   s_emb [64,16,2048] f32, q_emb [64,512,2048] f32
//   out = concat(log_p_y [64,512,64] f32, ce_loss f32, acc f32)
//
// dist_kernel (round 5): 32 query rows per block, 4 waves = 2 row-tiles x
// 2 column-halves. Triple-buffered LDS chunks staged entirely via
// __builtin_amdgcn_global_load_lds (no VGPR round-trip, no ds_writes):
//   - q staged as f32, XOR-granule swizzle achieved by pre-swizzling the
//     per-lane GLOBAL source address (LDS dest linear, as gload_lds needs)
//   - proto staged from a pre-swizzled global table built by proto_part
// Loop order: barrier -> issue DMA(n+2 -> free buf) -> compute(n), so the
// vmcnt(0) drain inside __syncthreads lands a full compute phase after each
// chunk's issue (round-4 bug: issue directly before barrier = full drain).

typedef __attribute__((ext_vector_type(8))) short bf16x8;
typedef __attribute__((ext_vector_type(4))) float f32x4;

#define N_WAY 64
#define N_SHOT 16
#define N_QUERY 512
#define DIM 2048
#define N_ROWS (N_WAY * N_QUERY)      // 32768
#define OUT_LOGP (N_ROWS * N_WAY)     // 2097152
#define KSLICES 8
#define KS (DIM / KSLICES)            // 256
#define KC 64                         // dims per staged chunk
#define NC (DIM / KC)                 // 32 chunks
#define RB 32                         // rows per block
#define QCH (RB * KC * 4)             // 8192 B q chunk (f32)
#define PCH (N_WAY * KC * 2)          // 8192 B proto chunk (bf16)
#define BUFSZ (QCH + PCH)             // 16384

static __device__ __forceinline__ short f2bf(float x) {
  union { __hip_bfloat16 b; short s; } u;
  u.b = __float2bfloat16(x);
  return u.s;
}

static __device__ __forceinline__ void gl_lds16(const void* g, void* l) {
  __builtin_amdgcn_global_load_lds(
      (const __attribute__((address_space(1))) unsigned int*)g,
      (__attribute__((address_space(3))) unsigned int*)l, 16, 0, 0);
}

// ---------------------------------------------------------------------------
// Kernel 1: prototype means -> PRE-SWIZZLED bf16 proto table + partial sumsq.
// Layout: short index = (k>>6)*4096 + m*64 + (((k>>3)&7) ^ (m&7))*8 + (k&7)
// i.e. per 64-dim chunk, way m's granule g (8 bf16) sits at slot g^(m&7).
// A linear 16B/lane DMA of one chunk then lands exactly in swizzled LDS form.
__global__ void proto_part(const float* __restrict__ s_emb,
                           short* __restrict__ proto_sw,
                           float* __restrict__ c_part) {
  int b = blockIdx.x;          // 0..511
  int m = b >> 3;              // way 0..63
  int ks = b & 7;              // k-slice 0..7
  int t = threadIdx.x;         // 0..255
  int k = ks * KS + t;

  const float* base = s_emb + ((size_t)m * N_SHOT) * DIM + k;
  float s = 0.f;
#pragma unroll
  for (int j = 0; j < N_SHOT; ++j) s += base[(size_t)j * DIM];
  float p = s * (1.0f / N_SHOT);

  int idx = (k >> 6) * 4096 + m * 64 + ((((k >> 3) & 7) ^ (m & 7)) << 3) + (k & 7);
  proto_sw[idx] = f2bf(p);

  float sq = p * p;
#pragma unroll
  for (int off = 1; off < 64; off <<= 1) sq += __shfl_xor(sq, off);

  __shared__ float red[4];
  int lane = t & 63, w = t >> 6;
  if (lane == 0) red[w] = sq;
  __syncthreads();
  if (t == 0) {
    c_part[m * KSLICES + ks] = red[0] + red[1] + red[2] + red[3];
  }
}

// ---------------------------------------------------------------------------
// Kernel 2: finalize c[m] = |p_m|^2 / D, zero the scalar output slots
__global__ void proto_fin(const float* __restrict__ c_part,
                          float* __restrict__ c,
                          float* __restrict__ scalars) {
  int t = threadIdx.x; // 64 threads
  if (t < N_WAY) {
    float s = 0.f;
#pragma unroll
    for (int i = 0; i < KSLICES; ++i) s += c_part[t * KSLICES + i];
    c[t] = s * (1.0f / DIM);
  }
  if (t < 2) scalars[t] = 0.f;
}

// ---------------------------------------------------------------------------
// Kernel 3: main.
//   s_m = (2 q.p_m - |p_m|^2)/D ; log_p = s - lse(s) (sq_q cancels in softmax)
__launch_bounds__(256, 4)
__global__ void dist_kernel(const float* __restrict__ q,
                            const short* __restrict__ proto_sw,
                            const float* __restrict__ c,
                            float* __restrict__ out,
                            float* __restrict__ scalars) {
  __shared__ __align__(16) char lds[3][BUFSZ];
  __shared__ float ex[2][2][16][4];     // [pair][half][row][mx,e,bv,bi]
  __shared__ float bred[4][2];

  int tid = threadIdx.x;
  int wv = tid >> 6;
  int lane = tid & 63;
  int l15 = lane & 15;
  int g = lane >> 4;
  int row0 = blockIdx.x * RB;

  int pair = wv >> 1;            // which 16-row tile
  int half = wv & 1;             // which 32-col half
  int ctb = half * 2;            // first of this wave's two col-tiles
  int r32 = pair * 16 + l15;     // this lane's q row within block

  // DMA one chunk into buf: q (per-lane swizzled source, linear LDS) + proto
  auto issue_chunk = [&](int cix, char* buf) {
#pragma unroll
    for (int j = 0; j < 2; ++j) {
      int call = wv * 2 + j;                 // 0..7, 1 KB each
      int R = call * 4 + (lane >> 4);        // q row in block
      int d = (lane & 15) ^ (R & 15);        // content granule for this slot
      const float* src = q + (size_t)(row0 + R) * DIM + cix * KC + d * 4;
      gl_lds16(src, buf + call * 1024);
    }
    const char* psrc = (const char*)proto_sw + (size_t)cix * PCH;
#pragma unroll
    for (int j = 0; j < 2; ++j) {
      int call = wv * 2 + j;
      gl_lds16(psrc + call * 1024 + lane * 16, buf + QCH + call * 1024);
    }
  };

  f32x4 acc2[2];
  acc2[0] = (f32x4){0.f, 0.f, 0.f, 0.f};
  acc2[1] = (f32x4){0.f, 0.f, 0.f, 0.f};

  auto compute_chunk = [&](const char* buf) {
    const char* bq = buf;
    const char* bp = buf + QCH;
#pragma unroll
    for (int ks = 0; ks < 2; ++ks) {
      int gq = ks * 8 + g * 2;
      f32x4 lo = *reinterpret_cast<const f32x4*>(bq + r32 * 256 + ((gq ^ l15) << 4));
      f32x4 hi = *reinterpret_cast<const f32x4*>(bq + r32 * 256 + (((gq + 1) ^ l15) << 4));
      bf16x8 af;
      af[0] = f2bf(lo[0]); af[1] = f2bf(lo[1]); af[2] = f2bf(lo[2]); af[3] = f2bf(lo[3]);
      af[4] = f2bf(hi[0]); af[5] = f2bf(hi[1]); af[6] = f2bf(hi[2]); af[7] = f2bf(hi[3]);
#pragma unroll
      for (int c2 = 0; c2 < 2; ++c2) {
        int W = (ctb + c2) * 16 + l15;
        bf16x8 bv = *reinterpret_cast<const bf16x8*>(
            bp + W * 128 + (((ks * 4 + g) ^ (l15 & 7)) << 4));
        acc2[c2] = __builtin_amdgcn_mfma_f32_16x16x32_bf16(af, bv, acc2[c2], 0, 0, 0);
      }
    }
  };

  issue_chunk(0, lds[0]);
  issue_chunk(1, lds[1]);
  for (int n = 0; n < NC; ++n) {
    __syncthreads();                       // drains DMA: chunk n (and n+1) ready
    if (n + 2 < NC) issue_chunk(n + 2, lds[(n + 2) % 3]);  // free buf (n-1 done)
    compute_chunk(lds[n % 3]);
  }

  // ---- epilogue ----
  float cc[2];
  cc[0] = c[ctb * 16 + l15];
  cc[1] = c[(ctb + 1) * 16 + l15];

  const float scale = 2.0f / (float)DIM;
  float sv[2][4], mxa[4], ea[4], bva[4];
  int bia[4];

#pragma unroll
  for (int r = 0; r < 4; ++r) {
    sv[0][r] = acc2[0][r] * scale - cc[0];
    sv[1][r] = acc2[1][r] * scale - cc[1];

    float mx = fmaxf(sv[0][r], sv[1][r]);
#pragma unroll
    for (int off = 1; off < 16; off <<= 1) mx = fmaxf(mx, __shfl_xor(mx, off));
    float e = __expf(sv[0][r] - mx) + __expf(sv[1][r] - mx);
#pragma unroll
    for (int off = 1; off < 16; off <<= 1) e += __shfl_xor(e, off);

    float bv = sv[0][r]; int bi = ctb * 16 + l15;
    if (sv[1][r] > bv) { bv = sv[1][r]; bi = (ctb + 1) * 16 + l15; }
#pragma unroll
    for (int off = 1; off < 16; off <<= 1) {
      float ov = __shfl_xor(bv, off);
      int oi = __shfl_xor(bi, off);
      if (ov > bv || (ov == bv && oi < bi)) { bv = ov; bi = oi; }
    }
    mxa[r] = mx; ea[r] = e; bva[r] = bv; bia[r] = bi;
    if (l15 == 0) {
      ex[pair][half][g * 4 + r][0] = mx;
      ex[pair][half][g * 4 + r][1] = e;
      ex[pair][half][g * 4 + r][2] = bv;
      ex[pair][half][g * 4 + r][3] = (float)bi;
    }
  }
  __syncthreads();

  float ce_part = 0.f, ac_part = 0.f;
  int rowbase = row0 + pair * 16;
#pragma unroll
  for (int r = 0; r < 4; ++r) {
    int row = rowbase + g * 4 + r;
    int wy = row >> 9;

    float omx = ex[pair][half ^ 1][g * 4 + r][0];
    float oe  = ex[pair][half ^ 1][g * 4 + r][1];
    float obv = ex[pair][half ^ 1][g * 4 + r][2];
    int   obi = (int)ex[pair][half ^ 1][g * 4 + r][3];

    float M = fmaxf(mxa[r], omx);
    float E = ea[r] * __expf(mxa[r] - M) + oe * __expf(omx - M);
    float lse = M + __logf(E);

    size_t ob = (size_t)row * N_WAY + ctb * 16 + l15;
    out[ob]      = sv[0][r] - lse;
    out[ob + 16] = sv[1][r] - lse;

    // CE: the wave whose col-half contains wy adds lse - s_wy
    if (half == (wy >> 5) && l15 == (wy & 15)) {
      ce_part += lse - sv[(wy >> 4) & 1][r];
    }

    // combined argmax (first-occurrence tie-break; half0 cols < half1 cols)
    float fbv = bva[r]; int fbi = bia[r];
    if (obv > fbv || (obv == fbv && obi < fbi)) { fbv = obv; fbi = obi; }
    if (half == 0 && l15 == 0) ac_part += (fbi == wy) ? 1.0f : 0.0f;
  }

  // block-level scalar reduce, one atomic pair per block
#pragma unroll
  for (int off = 1; off < 64; off <<= 1) {
    ce_part += __shfl_xor(ce_part, off);
    ac_part += __shfl_xor(ac_part, off);
  }
  if (lane == 0) { bred[wv][0] = ce_part; bred[wv][1] = ac_part; }
  __syncthreads();
  if (tid == 0) {
    float C = bred[0][0] + bred[1][0] + bred[2][0] + bred[3][0];
    float A = bred[0][1] + bred[1][1] + bred[2][1] + bred[3][1];
    atomicAdd(&scalars[0], C * (1.0f / N_ROWS));
    atomicAdd(&scalars[1], A * (1.0f / N_ROWS));
  }
}

// ---------------------------------------------------------------------------
extern "C" void kernel_launch(void* const* d_in, const int* in_sizes, int n_in,
                              void* d_out, int out_size, void* d_ws, size_t ws_size,
                              hipStream_t stream) {
  const float* s_emb = (const float*)d_in[0];
  const float* q_emb = (const float*)d_in[1];
  float* out = (float*)d_out;
  char* ws = (char*)d_ws;

  short* proto_sw = (short*)ws;                                // 256 KB
  float* c_part = (float*)(ws + 256 * 1024);                   // 2 KB
  float* c = (float*)(ws + 256 * 1024 + 4096);                 // 256 B
  float* scalars = out + OUT_LOGP;

  hipLaunchKernelGGL(proto_part, dim3(512), dim3(256), 0, stream, s_emb, proto_sw, c_part);
  hipLaunchKernelGGL(proto_fin, dim3(1), dim3(64), 0, stream, c_part, c, scalars);
  hipLaunchKernelGGL(dist_kernel, dim3(N_ROWS / RB), dim3(256), 0, stream,
                     q_emb, proto_sw, c, out, scalars);
}

// Round 6
// 91.052 us; speedup vs baseline: 1.6543x; 1.1195x over previous
//
#include <hip/hip_runtime.h>
#include <hip/hip_bf16.h>

// Prototypical nets head:
//   s_emb [64,16,2048] f32, q_emb [64,512,2048] f32
//   out = concat(log_p_y [64,512,64] f32, ce_loss f32, acc f32)
//
// dist_kernel (round 6): same staging as round 5 (triple-buffered LDS chunks
// via global_load_lds; q f32 with source-address swizzle; proto from a
// pre-swizzled global table) but the per-chunk __syncthreads (which drains
// vmcnt to 0 -- the round-4/5 limiter) is replaced by the counted idiom:
//   s_waitcnt vmcnt(4)  (own chunk-n DMAs done; chunk n+1 stays in flight)
//   s_barrier           (all waves' chunk-n writes visible)
//   issue(n+2)          (safe: barrier proves compute(n-1) done block-wide)
//   compute(n)
// so the DMA queue is never drained until the tail (T3/T4, m218).

typedef __attribute__((ext_vector_type(8))) short bf16x8;
typedef __attribute__((ext_vector_type(4))) float f32x4;

#define N_WAY 64
#define N_SHOT 16
#define N_QUERY 512
#define DIM 2048
#define N_ROWS (N_WAY * N_QUERY)      // 32768
#define OUT_LOGP (N_ROWS * N_WAY)     // 2097152
#define KSLICES 8
#define KS (DIM / KSLICES)            // 256
#define KC 64                         // dims per staged chunk
#define NC (DIM / KC)                 // 32 chunks
#define RB 32                         // rows per block
#define QCH (RB * KC * 4)             // 8192 B q chunk (f32)
#define PCH (N_WAY * KC * 2)          // 8192 B proto chunk (bf16)
#define BUFSZ (QCH + PCH)             // 16384

static __device__ __forceinline__ short f2bf(float x) {
  union { __hip_bfloat16 b; short s; } u;
  u.b = __float2bfloat16(x);
  return u.s;
}

static __device__ __forceinline__ void gl_lds16(const void* g, void* l) {
  __builtin_amdgcn_global_load_lds(
      (const __attribute__((address_space(1))) unsigned int*)g,
      (__attribute__((address_space(3))) unsigned int*)l, 16, 0, 0);
}

// ---------------------------------------------------------------------------
// Kernel 1: prototype means -> PRE-SWIZZLED bf16 proto table + partial sumsq.
// Layout: short index = (k>>6)*4096 + m*64 + (((k>>3)&7) ^ (m&7))*8 + (k&7)
__global__ void proto_part(const float* __restrict__ s_emb,
                           short* __restrict__ proto_sw,
                           float* __restrict__ c_part) {
  int b = blockIdx.x;          // 0..511
  int m = b >> 3;              // way 0..63
  int ks = b & 7;              // k-slice 0..7
  int t = threadIdx.x;         // 0..255
  int k = ks * KS + t;

  const float* base = s_emb + ((size_t)m * N_SHOT) * DIM + k;
  float s = 0.f;
#pragma unroll
  for (int j = 0; j < N_SHOT; ++j) s += base[(size_t)j * DIM];
  float p = s * (1.0f / N_SHOT);

  int idx = (k >> 6) * 4096 + m * 64 + ((((k >> 3) & 7) ^ (m & 7)) << 3) + (k & 7);
  proto_sw[idx] = f2bf(p);

  float sq = p * p;
#pragma unroll
  for (int off = 1; off < 64; off <<= 1) sq += __shfl_xor(sq, off);

  __shared__ float red[4];
  int lane = t & 63, w = t >> 6;
  if (lane == 0) red[w] = sq;
  __syncthreads();
  if (t == 0) {
    c_part[m * KSLICES + ks] = red[0] + red[1] + red[2] + red[3];
  }
}

// ---------------------------------------------------------------------------
// Kernel 2: finalize c[m] = |p_m|^2 / D, zero the scalar output slots
__global__ void proto_fin(const float* __restrict__ c_part,
                          float* __restrict__ c,
                          float* __restrict__ scalars) {
  int t = threadIdx.x; // 64 threads
  if (t < N_WAY) {
    float s = 0.f;
#pragma unroll
    for (int i = 0; i < KSLICES; ++i) s += c_part[t * KSLICES + i];
    c[t] = s * (1.0f / DIM);
  }
  if (t < 2) scalars[t] = 0.f;
}

// ---------------------------------------------------------------------------
// Kernel 3: main.
//   s_m = (2 q.p_m - |p_m|^2)/D ; log_p = s - lse(s) (sq_q cancels in softmax)
__launch_bounds__(256, 4)
__global__ void dist_kernel(const float* __restrict__ q,
                            const short* __restrict__ proto_sw,
                            const float* __restrict__ c,
                            float* __restrict__ out,
                            float* __restrict__ scalars) {
  __shared__ __align__(16) char lds[3][BUFSZ];
  __shared__ float ex[2][2][16][4];     // [pair][half][row][mx,e,bv,bi]
  __shared__ float bred[4][2];

  int tid = threadIdx.x;
  int wv = tid >> 6;
  int lane = tid & 63;
  int l15 = lane & 15;
  int g = lane >> 4;
  int row0 = blockIdx.x * RB;

  int pair = wv >> 1;            // which 16-row tile
  int half = wv & 1;             // which 32-col half
  int ctb = half * 2;            // first of this wave's two col-tiles
  int r32 = pair * 16 + l15;     // this lane's q row within block

  // DMA one chunk into buf: q (per-lane swizzled source, linear LDS) + proto.
  // Exactly 4 global_load_lds instructions per wave per chunk (vmcnt unit).
  auto issue_chunk = [&](int cix, char* buf) {
#pragma unroll
    for (int j = 0; j < 2; ++j) {
      int call = wv * 2 + j;                 // 0..7, 1 KB each
      int R = call * 4 + (lane >> 4);        // q row in block
      int d = (lane & 15) ^ (R & 15);        // content granule for this slot
      const float* src = q + (size_t)(row0 + R) * DIM + cix * KC + d * 4;
      gl_lds16(src, buf + call * 1024);
    }
    const char* psrc = (const char*)proto_sw + (size_t)cix * PCH;
#pragma unroll
    for (int j = 0; j < 2; ++j) {
      int call = wv * 2 + j;
      gl_lds16(psrc + call * 1024 + lane * 16, buf + QCH + call * 1024);
    }
  };

  f32x4 acc2[2];
  acc2[0] = (f32x4){0.f, 0.f, 0.f, 0.f};
  acc2[1] = (f32x4){0.f, 0.f, 0.f, 0.f};

  auto compute_chunk = [&](const char* buf) {
    const char* bq = buf;
    const char* bp = buf + QCH;
#pragma unroll
    for (int ks = 0; ks < 2; ++ks) {
      int gq = ks * 8 + g * 2;
      f32x4 lo = *reinterpret_cast<const f32x4*>(bq + r32 * 256 + ((gq ^ l15) << 4));
      f32x4 hi = *reinterpret_cast<const f32x4*>(bq + r32 * 256 + (((gq + 1) ^ l15) << 4));
      bf16x8 af;
      af[0] = f2bf(lo[0]); af[1] = f2bf(lo[1]); af[2] = f2bf(lo[2]); af[3] = f2bf(lo[3]);
      af[4] = f2bf(hi[0]); af[5] = f2bf(hi[1]); af[6] = f2bf(hi[2]); af[7] = f2bf(hi[3]);
#pragma unroll
      for (int c2 = 0; c2 < 2; ++c2) {
        int W = (ctb + c2) * 16 + l15;
        bf16x8 bv = *reinterpret_cast<const bf16x8*>(
            bp + W * 128 + (((ks * 4 + g) ^ (l15 & 7)) << 4));
        acc2[c2] = __builtin_amdgcn_mfma_f32_16x16x32_bf16(af, bv, acc2[c2], 0, 0, 0);
      }
    }
  };

  issue_chunk(0, lds[0]);
  issue_chunk(1, lds[1]);
  char* cbuf = lds[0];   // compute buffer (chunk n)
  char* nbuf = lds[1];   // next (chunk n+1, in flight)
  char* ibuf = lds[2];   // issue target (chunk n+2)
  for (int n = 0; n < NC - 1; ++n) {
    // own 4 newest DMAs (chunk n+1) may stay outstanding; chunk n is landed
    asm volatile("s_waitcnt vmcnt(4)" ::: "memory");
    __builtin_amdgcn_s_barrier();          // all waves' chunk-n writes visible
    if (n + 2 < NC) issue_chunk(n + 2, ibuf);  // ibuf last read at compute(n-1)
    compute_chunk(cbuf);
    char* t0 = cbuf; cbuf = nbuf; nbuf = ibuf; ibuf = t0;
  }
  asm volatile("s_waitcnt vmcnt(0)" ::: "memory");
  __builtin_amdgcn_s_barrier();
  compute_chunk(cbuf);

  // ---- epilogue ----
  float cc[2];
  cc[0] = c[ctb * 16 + l15];
  cc[1] = c[(ctb + 1) * 16 + l15];

  const float scale = 2.0f / (float)DIM;
  float sv[2][4], mxa[4], ea[4], bva[4];
  int bia[4];

#pragma unroll
  for (int r = 0; r < 4; ++r) {
    sv[0][r] = acc2[0][r] * scale - cc[0];
    sv[1][r] = acc2[1][r] * scale - cc[1];

    float mx = fmaxf(sv[0][r], sv[1][r]);
#pragma unroll
    for (int off = 1; off < 16; off <<= 1) mx = fmaxf(mx, __shfl_xor(mx, off));
    float e = __expf(sv[0][r] - mx) + __expf(sv[1][r] - mx);
#pragma unroll
    for (int off = 1; off < 16; off <<= 1) e += __shfl_xor(e, off);

    float bv = sv[0][r]; int bi = ctb * 16 + l15;
    if (sv[1][r] > bv) { bv = sv[1][r]; bi = (ctb + 1) * 16 + l15; }
#pragma unroll
    for (int off = 1; off < 16; off <<= 1) {
      float ov = __shfl_xor(bv, off);
      int oi = __shfl_xor(bi, off);
      if (ov > bv || (ov == bv && oi < bi)) { bv = ov; bi = oi; }
    }
    mxa[r] = mx; ea[r] = e; bva[r] = bv; bia[r] = bi;
    if (l15 == 0) {
      ex[pair][half][g * 4 + r][0] = mx;
      ex[pair][half][g * 4 + r][1] = e;
      ex[pair][half][g * 4 + r][2] = bv;
      ex[pair][half][g * 4 + r][3] = (float)bi;
    }
  }
  __syncthreads();

  float ce_part = 0.f, ac_part = 0.f;
  int rowbase = row0 + pair * 16;
#pragma unroll
  for (int r = 0; r < 4; ++r) {
    int row = rowbase + g * 4 + r;
    int wy = row >> 9;

    float omx = ex[pair][half ^ 1][g * 4 + r][0];
    float oe  = ex[pair][half ^ 1][g * 4 + r][1];
    float obv = ex[pair][half ^ 1][g * 4 + r][2];
    int   obi = (int)ex[pair][half ^ 1][g * 4 + r][3];

    float M = fmaxf(mxa[r], omx);
    float E = ea[r] * __expf(mxa[r] - M) + oe * __expf(omx - M);
    float lse = M + __logf(E);

    size_t ob = (size_t)row * N_WAY + ctb * 16 + l15;
    out[ob]      = sv[0][r] - lse;
    out[ob + 16] = sv[1][r] - lse;

    // CE: the wave whose col-half contains wy adds lse - s_wy
    if (half == (wy >> 5) && l15 == (wy & 15)) {
      ce_part += lse - sv[(wy >> 4) & 1][r];
    }

    // combined argmax (first-occurrence tie-break; half0 cols < half1 cols)
    float fbv = bva[r]; int fbi = bia[r];
    if (obv > fbv || (obv == fbv && obi < fbi)) { fbv = obv; fbi = obi; }
    if (half == 0 && l15 == 0) ac_part += (fbi == wy) ? 1.0f : 0.0f;
  }

  // block-level scalar reduce, one atomic pair per block
#pragma unroll
  for (int off = 1; off < 64; off <<= 1) {
    ce_part += __shfl_xor(ce_part, off);
    ac_part += __shfl_xor(ac_part, off);
  }
  if (lane == 0) { bred[wv][0] = ce_part; bred[wv][1] = ac_part; }
  __syncthreads();
  if (tid == 0) {
    float C = bred[0][0] + bred[1][0] + bred[2][0] + bred[3][0];
    float A = bred[0][1] + bred[1][1] + bred[2][1] + bred[3][1];
    atomicAdd(&scalars[0], C * (1.0f / N_ROWS));
    atomicAdd(&scalars[1], A * (1.0f / N_ROWS));
  }
}

// ---------------------------------------------------------------------------
extern "C" void kernel_launch(void* const* d_in, const int* in_sizes, int n_in,
                              void* d_out, int out_size, void* d_ws, size_t ws_size,
                              hipStream_t stream) {
  const float* s_emb = (const float*)d_in[0];
  const float* q_emb = (const float*)d_in[1];
  float* out = (float*)d_out;
  char* ws = (char*)d_ws;

  short* proto_sw = (short*)ws;                                // 256 KB
  float* c_part = (float*)(ws + 256 * 1024);                   // 2 KB
  float* c = (float*)(ws + 256 * 1024 + 4096);                 // 256 B
  float* scalars = out + OUT_LOGP;

  hipLaunchKernelGGL(proto_part, dim3(512), dim3(256), 0, stream, s_emb, proto_sw, c_part);
  hipLaunchKernelGGL(proto_fin, dim3(1), dim3(64), 0, stream, c_part, c, scalars);
  hipLaunchKernelGGL(dist_kernel, dim3(N_ROWS / RB), dim3(256), 0, stream,
                     q_emb, proto_sw, c, out, scalars);
}

// Round 7
// 58.859 us; speedup vs baseline: 2.5592x; 1.5470x over previous
//
#include <hip/hip_runtime.h>
#include <hip/hip_bf16.h>

// Prototypical nets head:
//   s_emb [64,16,2048] f32, q_emb [64,512,2048] f32
//   out = concat(log_p_y [64,512,64] f32, ce_loss f32, acc f32)
//
// dist_kernel (round 7): RB=128 rows/block, 512 threads = 8 waves, each wave
// owns 16 rows x all 64 cols (no cross-wave softmax). Triple-buffered 40 KB
// LDS chunks (q f32 32 KB + proto bf16 8 KB) staged via global_load_lds with
// counted s_waitcnt vmcnt(5) + raw s_barrier (never drain to 0 mid-loop).
// Rationale: round-6 limiter was per-CU vector-path bytes (~12 B/cy ceiling);
// proto restage dropped from 256 MB (1024 blocks) to 64 MB (256 blocks).

typedef __attribute__((ext_vector_type(8))) short bf16x8;
typedef __attribute__((ext_vector_type(4))) float f32x4;

#define N_WAY 64
#define N_SHOT 16
#define N_QUERY 512
#define DIM 2048
#define N_ROWS (N_WAY * N_QUERY)      // 32768
#define OUT_LOGP (N_ROWS * N_WAY)     // 2097152
#define KSLICES 8
#define KS (DIM / KSLICES)            // 256
#define KC 64                         // dims per staged chunk
#define NC (DIM / KC)                 // 32 chunks
#define RB 128                        // rows per block
#define QCH (RB * KC * 4)             // 32768 B q chunk (f32)
#define PCH (N_WAY * KC * 2)          // 8192 B proto chunk (bf16)
#define BUFSZ (QCH + PCH)             // 40960

static __device__ __forceinline__ short f2bf(float x) {
  union { __hip_bfloat16 b; short s; } u;
  u.b = __float2bfloat16(x);
  return u.s;
}

static __device__ __forceinline__ void gl_lds16(const void* g, void* l) {
  __builtin_amdgcn_global_load_lds(
      (const __attribute__((address_space(1))) unsigned int*)g,
      (__attribute__((address_space(3))) unsigned int*)l, 16, 0, 0);
}

// ---------------------------------------------------------------------------
// Kernel 1: prototype means -> PRE-SWIZZLED bf16 proto table + partial sumsq.
// Layout: short index = (k>>6)*4096 + m*64 + (((k>>3)&7) ^ (m&7))*8 + (k&7)
__global__ void proto_part(const float* __restrict__ s_emb,
                           short* __restrict__ proto_sw,
                           float* __restrict__ c_part) {
  int b = blockIdx.x;          // 0..511
  int m = b >> 3;              // way 0..63
  int ks = b & 7;              // k-slice 0..7
  int t = threadIdx.x;         // 0..255
  int k = ks * KS + t;

  const float* base = s_emb + ((size_t)m * N_SHOT) * DIM + k;
  float s = 0.f;
#pragma unroll
  for (int j = 0; j < N_SHOT; ++j) s += base[(size_t)j * DIM];
  float p = s * (1.0f / N_SHOT);

  int idx = (k >> 6) * 4096 + m * 64 + ((((k >> 3) & 7) ^ (m & 7)) << 3) + (k & 7);
  proto_sw[idx] = f2bf(p);

  float sq = p * p;
#pragma unroll
  for (int off = 1; off < 64; off <<= 1) sq += __shfl_xor(sq, off);

  __shared__ float red[4];
  int lane = t & 63, w = t >> 6;
  if (lane == 0) red[w] = sq;
  __syncthreads();
  if (t == 0) {
    c_part[m * KSLICES + ks] = red[0] + red[1] + red[2] + red[3];
  }
}

// ---------------------------------------------------------------------------
// Kernel 2: finalize c[m] = |p_m|^2 / D, zero the scalar output slots
__global__ void proto_fin(const float* __restrict__ c_part,
                          float* __restrict__ c,
                          float* __restrict__ scalars) {
  int t = threadIdx.x; // 64 threads
  if (t < N_WAY) {
    float s = 0.f;
#pragma unroll
    for (int i = 0; i < KSLICES; ++i) s += c_part[t * KSLICES + i];
    c[t] = s * (1.0f / DIM);
  }
  if (t < 2) scalars[t] = 0.f;
}

// ---------------------------------------------------------------------------
// Kernel 3: main.
//   s_m = (2 q.p_m - |p_m|^2)/D ; log_p = s - lse(s) (sq_q cancels in softmax)
// LDS q layout: row r, 16B-granule slot s at byte r*256 + s*16, content
// granule d = s ^ (r&15) (source-address pre-swizzle; LDS dest linear).
// LDS proto layout: way W, k-granule gk at slot gk ^ (W&7) (pre-swizzled
// global table). Both give <=2-way phase conflicts on ds_read_b128 (free).
__launch_bounds__(512, 2)
__global__ void dist_kernel(const float* __restrict__ q,
                            const short* __restrict__ proto_sw,
                            const float* __restrict__ c,
                            float* __restrict__ out,
                            float* __restrict__ scalars) {
  __shared__ __align__(16) char lds[3][BUFSZ];
  __shared__ float bred[8][2];

  int tid = threadIdx.x;
  int wv = tid >> 6;             // 0..7
  int lane = tid & 63;
  int l15 = lane & 15;
  int g = lane >> 4;
  int row0 = blockIdx.x * RB;

  // 5 global_load_lds per wave per chunk (the vmcnt unit): 4 q + 1 proto
  auto issue_chunk = [&](int cix, char* buf) {
#pragma unroll
    for (int j = 0; j < 4; ++j) {
      int call = wv * 4 + j;                 // 0..31, 1 KB each
      int R = call * 4 + (lane >> 4);        // q row in block (4 rows/call)
      int s = lane & 15;                     // slot within row
      int d = s ^ (R & 15);                  // content granule for this slot
      const float* src = q + (size_t)(row0 + R) * DIM + cix * KC + d * 4;
      gl_lds16(src, buf + call * 1024 + lane * 16);
    }
    const char* psrc = (const char*)proto_sw + (size_t)cix * PCH;
    gl_lds16(psrc + wv * 1024 + lane * 16, buf + QCH + wv * 1024 + lane * 16);
  };

  f32x4 acc[4];
#pragma unroll
  for (int ct = 0; ct < 4; ++ct) acc[ct] = (f32x4){0.f, 0.f, 0.f, 0.f};

  int arow = wv * 16 + l15;      // this lane's q row within block
  auto compute_chunk = [&](const char* buf) {
    const char* bq = buf;
    const char* bp = buf + QCH;
#pragma unroll
    for (int ks = 0; ks < 2; ++ks) {
      int gq = ks * 8 + g * 2;
      f32x4 lo = *reinterpret_cast<const f32x4*>(
          bq + arow * 256 + ((gq ^ (arow & 15)) << 4));
      f32x4 hi = *reinterpret_cast<const f32x4*>(
          bq + arow * 256 + (((gq + 1) ^ (arow & 15)) << 4));
      bf16x8 af;
      af[0] = f2bf(lo[0]); af[1] = f2bf(lo[1]); af[2] = f2bf(lo[2]); af[3] = f2bf(lo[3]);
      af[4] = f2bf(hi[0]); af[5] = f2bf(hi[1]); af[6] = f2bf(hi[2]); af[7] = f2bf(hi[3]);
#pragma unroll
      for (int ct = 0; ct < 4; ++ct) {
        int W = ct * 16 + l15;
        bf16x8 bv = *reinterpret_cast<const bf16x8*>(
            bp + W * 128 + (((ks * 4 + g) ^ (W & 7)) << 4));
        acc[ct] = __builtin_amdgcn_mfma_f32_16x16x32_bf16(af, bv, acc[ct], 0, 0, 0);
      }
    }
  };

  issue_chunk(0, lds[0]);
  issue_chunk(1, lds[1]);
  char* cbuf = lds[0];   // compute buffer (chunk n)
  char* nbuf = lds[1];   // next (chunk n+1, in flight)
  char* ibuf = lds[2];   // issue target (chunk n+2)
  for (int n = 0; n < NC - 1; ++n) {
    // own 5 newest DMAs (chunk n+1) may stay outstanding; chunk n has landed
    asm volatile("s_waitcnt vmcnt(5)" ::: "memory");
    __builtin_amdgcn_s_barrier();          // all waves' chunk-n writes visible
    if (n + 2 < NC) issue_chunk(n + 2, ibuf);  // ibuf last read at compute(n-1)
    compute_chunk(cbuf);
    char* t0 = cbuf; cbuf = nbuf; nbuf = ibuf; ibuf = t0;
  }
  asm volatile("s_waitcnt vmcnt(0)" ::: "memory");
  __builtin_amdgcn_s_barrier();
  compute_chunk(cbuf);

  // ---- epilogue: each wave finishes its own 16 rows (all 64 cols) ----
  float cc[4];
#pragma unroll
  for (int ct = 0; ct < 4; ++ct) cc[ct] = c[ct * 16 + l15];

  const float scale = 2.0f / (float)DIM;
  float ce_part = 0.f;
  float ac_part = 0.f;
  int rowbase = row0 + wv * 16;

#pragma unroll
  for (int r = 0; r < 4; ++r) {
    int row = rowbase + g * 4 + r;
    int wy = row >> 9;           // true class = row / N_QUERY

    float s0 = acc[0][r] * scale - cc[0];
    float s1 = acc[1][r] * scale - cc[1];
    float s2 = acc[2][r] * scale - cc[2];
    float s3 = acc[3][r] * scale - cc[3];

    float mx = fmaxf(fmaxf(s0, s1), fmaxf(s2, s3));
#pragma unroll
    for (int off = 1; off < 16; off <<= 1) mx = fmaxf(mx, __shfl_xor(mx, off));

    float e = __expf(s0 - mx) + __expf(s1 - mx) + __expf(s2 - mx) + __expf(s3 - mx);
#pragma unroll
    for (int off = 1; off < 16; off <<= 1) e += __shfl_xor(e, off);
    float lse = mx + __logf(e);

    size_t ob = (size_t)row * N_WAY + l15;
    out[ob]      = s0 - lse;
    out[ob + 16] = s1 - lse;
    out[ob + 32] = s2 - lse;
    out[ob + 48] = s3 - lse;

    // CE: -log_p[row, wy] = lse - s_wy ; col ct*16+l15 == wy
    if (l15 == (wy & 15)) {
      int ct = wy >> 4;
      float sw = (ct == 0) ? s0 : (ct == 1) ? s1 : (ct == 2) ? s2 : s3;
      ce_part += lse - sw;
    }

    // argmax with first-occurrence tie-break
    float bv = s0; int bi = l15;
    if (s1 > bv) { bv = s1; bi = l15 + 16; }
    if (s2 > bv) { bv = s2; bi = l15 + 32; }
    if (s3 > bv) { bv = s3; bi = l15 + 48; }
#pragma unroll
    for (int off = 1; off < 16; off <<= 1) {
      float ov = __shfl_xor(bv, off);
      int oi = __shfl_xor(bi, off);
      if (ov > bv || (ov == bv && oi < bi)) { bv = ov; bi = oi; }
    }
    if (l15 == 0) ac_part += (bi == wy) ? 1.0f : 0.0f;
  }

  // block-level scalar reduce, one atomic pair per block
#pragma unroll
  for (int off = 1; off < 64; off <<= 1) {
    ce_part += __shfl_xor(ce_part, off);
    ac_part += __shfl_xor(ac_part, off);
  }
  if (lane == 0) { bred[wv][0] = ce_part; bred[wv][1] = ac_part; }
  __syncthreads();
  if (tid == 0) {
    float C = 0.f, A = 0.f;
#pragma unroll
    for (int j = 0; j < 8; ++j) { C += bred[j][0]; A += bred[j][1]; }
    atomicAdd(&scalars[0], C * (1.0f / N_ROWS));
    atomicAdd(&scalars[1], A * (1.0f / N_ROWS));
  }
}

// ---------------------------------------------------------------------------
extern "C" void kernel_launch(void* const* d_in, const int* in_sizes, int n_in,
                              void* d_out, int out_size, void* d_ws, size_t ws_size,
                              hipStream_t stream) {
  const float* s_emb = (const float*)d_in[0];
  const float* q_emb = (const float*)d_in[1];
  float* out = (float*)d_out;
  char* ws = (char*)d_ws;

  short* proto_sw = (short*)ws;                                // 256 KB
  float* c_part = (float*)(ws + 256 * 1024);                   // 2 KB
  float* c = (float*)(ws + 256 * 1024 + 4096);                 // 256 B
  float* scalars = out + OUT_LOGP;

  hipLaunchKernelGGL(proto_part, dim3(512), dim3(256), 0, stream, s_emb, proto_sw, c_part);
  hipLaunchKernelGGL(proto_fin, dim3(1), dim3(64), 0, stream, c_part, c, scalars);
  hipLaunchKernelGGL(dist_kernel, dim3(N_ROWS / RB), dim3(512), 0, stream,
                     q_emb, proto_sw, c, out, scalars);
}

// Round 8
// 56.864 us; speedup vs baseline: 2.6489x; 1.0351x over previous
//
#include <hip/hip_runtime.h>
#include <hip/hip_bf16.h>

// Prototypical nets head:
//   s_emb [64,16,2048] f32, q_emb [64,512,2048] f32
//   out = concat(log_p_y [64,512,64] f32, ce_loss f32, acc f32)
//
// Round 8: round-7 pipeline (RB=128, 8 waves, triple-buffered 40 KB chunks,
// global_load_lds staging, counted s_waitcnt vmcnt(5) + raw s_barrier)
// with proto_fin fused away: each dist block reduces c_part -> cfin in LDS
// before issuing any DMA (so the compiler's wait for these loads can't
// drain the staging queue), and proto_part block 0 zeroes the scalar slots.

typedef __attribute__((ext_vector_type(8))) short bf16x8;
typedef __attribute__((ext_vector_type(4))) float f32x4;

#define N_WAY 64
#define N_SHOT 16
#define N_QUERY 512
#define DIM 2048
#define N_ROWS (N_WAY * N_QUERY)      // 32768
#define OUT_LOGP (N_ROWS * N_WAY)     // 2097152
#define KSLICES 8
#define KS (DIM / KSLICES)            // 256
#define KC 64                         // dims per staged chunk
#define NC (DIM / KC)                 // 32 chunks
#define RB 128                        // rows per block
#define QCH (RB * KC * 4)             // 32768 B q chunk (f32)
#define PCH (N_WAY * KC * 2)          // 8192 B proto chunk (bf16)
#define BUFSZ (QCH + PCH)             // 40960

static __device__ __forceinline__ short f2bf(float x) {
  union { __hip_bfloat16 b; short s; } u;
  u.b = __float2bfloat16(x);
  return u.s;
}

static __device__ __forceinline__ void gl_lds16(const void* g, void* l) {
  __builtin_amdgcn_global_load_lds(
      (const __attribute__((address_space(1))) unsigned int*)g,
      (__attribute__((address_space(3))) unsigned int*)l, 16, 0, 0);
}

// ---------------------------------------------------------------------------
// Kernel 1: prototype means -> PRE-SWIZZLED bf16 proto table + partial sumsq.
// Layout: short index = (k>>6)*4096 + m*64 + (((k>>3)&7) ^ (m&7))*8 + (k&7)
// Block 0 also zeroes the scalar output slots (runs before dist's atomics).
__global__ void proto_part(const float* __restrict__ s_emb,
                           short* __restrict__ proto_sw,
                           float* __restrict__ c_part,
                           float* __restrict__ scalars) {
  int b = blockIdx.x;          // 0..511
  int m = b >> 3;              // way 0..63
  int ks = b & 7;              // k-slice 0..7
  int t = threadIdx.x;         // 0..255
  int k = ks * KS + t;

  if (b == 0 && t < 2) scalars[t] = 0.f;

  const float* base = s_emb + ((size_t)m * N_SHOT) * DIM + k;
  float s = 0.f;
#pragma unroll
  for (int j = 0; j < N_SHOT; ++j) s += base[(size_t)j * DIM];
  float p = s * (1.0f / N_SHOT);

  int idx = (k >> 6) * 4096 + m * 64 + ((((k >> 3) & 7) ^ (m & 7)) << 3) + (k & 7);
  proto_sw[idx] = f2bf(p);

  float sq = p * p;
#pragma unroll
  for (int off = 1; off < 64; off <<= 1) sq += __shfl_xor(sq, off);

  __shared__ float red[4];
  int lane = t & 63, w = t >> 6;
  if (lane == 0) red[w] = sq;
  __syncthreads();
  if (t == 0) {
    c_part[m * KSLICES + ks] = red[0] + red[1] + red[2] + red[3];
  }
}

// ---------------------------------------------------------------------------
// Kernel 2: main.
//   s_m = (2 q.p_m - |p_m|^2)/D ; log_p = s - lse(s) (sq_q cancels in softmax)
// LDS q layout: row r, 16B-granule slot s at byte r*256 + s*16, content
// granule d = s ^ (r&15) (source-address pre-swizzle; LDS dest linear).
// LDS proto layout: way W, k-granule gk at slot gk ^ (W&7) (pre-swizzled
// global table). Both give <=2-way phase conflicts on ds_read_b128 (free).
__launch_bounds__(512, 2)
__global__ void dist_kernel(const float* __restrict__ q,
                            const short* __restrict__ proto_sw,
                            const float* __restrict__ c_part,
                            float* __restrict__ out,
                            float* __restrict__ scalars) {
  __shared__ __align__(16) char lds[3][BUFSZ];
  __shared__ float bred[8][2];
  __shared__ float cfin[N_WAY];

  int tid = threadIdx.x;
  int wv = tid >> 6;             // 0..7
  int lane = tid & 63;
  int l15 = lane & 15;
  int g = lane >> 4;
  int row0 = blockIdx.x * RB;

  // finalize c[m] = |p_m|^2 / D in LDS (replaces the proto_fin kernel).
  // Done BEFORE any DMA issue so the compiler's waitcnt for these loads
  // cannot drain the staging queue. Visible after the first s_barrier.
  if (tid < N_WAY) {
    float s = 0.f;
#pragma unroll
    for (int i = 0; i < KSLICES; ++i) s += c_part[tid * KSLICES + i];
    cfin[tid] = s * (1.0f / DIM);
  }

  // 5 global_load_lds per wave per chunk (the vmcnt unit): 4 q + 1 proto
  auto issue_chunk = [&](int cix, char* buf) {
#pragma unroll
    for (int j = 0; j < 4; ++j) {
      int call = wv * 4 + j;                 // 0..31, 1 KB each
      int R = call * 4 + (lane >> 4);        // q row in block (4 rows/call)
      int s = lane & 15;                     // slot within row
      int d = s ^ (R & 15);                  // content granule for this slot
      const float* src = q + (size_t)(row0 + R) * DIM + cix * KC + d * 4;
      gl_lds16(src, buf + call * 1024 + lane * 16);
    }
    const char* psrc = (const char*)proto_sw + (size_t)cix * PCH;
    gl_lds16(psrc + wv * 1024 + lane * 16, buf + QCH + wv * 1024 + lane * 16);
  };

  f32x4 acc[4];
#pragma unroll
  for (int ct = 0; ct < 4; ++ct) acc[ct] = (f32x4){0.f, 0.f, 0.f, 0.f};

  int arow = wv * 16 + l15;      // this lane's q row within block
  auto compute_chunk = [&](const char* buf) {
    const char* bq = buf;
    const char* bp = buf + QCH;
#pragma unroll
    for (int ks = 0; ks < 2; ++ks) {
      int gq = ks * 8 + g * 2;
      f32x4 lo = *reinterpret_cast<const f32x4*>(
          bq + arow * 256 + ((gq ^ (arow & 15)) << 4));
      f32x4 hi = *reinterpret_cast<const f32x4*>(
          bq + arow * 256 + (((gq + 1) ^ (arow & 15)) << 4));
      bf16x8 af;
      af[0] = f2bf(lo[0]); af[1] = f2bf(lo[1]); af[2] = f2bf(lo[2]); af[3] = f2bf(lo[3]);
      af[4] = f2bf(hi[0]); af[5] = f2bf(hi[1]); af[6] = f2bf(hi[2]); af[7] = f2bf(hi[3]);
#pragma unroll
      for (int ct = 0; ct < 4; ++ct) {
        int W = ct * 16 + l15;
        bf16x8 bv = *reinterpret_cast<const bf16x8*>(
            bp + W * 128 + (((ks * 4 + g) ^ (W & 7)) << 4));
        acc[ct] = __builtin_amdgcn_mfma_f32_16x16x32_bf16(af, bv, acc[ct], 0, 0, 0);
      }
    }
  };

  issue_chunk(0, lds[0]);
  issue_chunk(1, lds[1]);
  char* cbuf = lds[0];   // compute buffer (chunk n)
  char* nbuf = lds[1];   // next (chunk n+1, in flight)
  char* ibuf = lds[2];   // issue target (chunk n+2)
  for (int n = 0; n < NC - 1; ++n) {
    // own 5 newest DMAs (chunk n+1) may stay outstanding; chunk n has landed
    asm volatile("s_waitcnt vmcnt(5)" ::: "memory");
    __builtin_amdgcn_s_barrier();          // all waves' chunk-n writes visible
    if (n + 2 < NC) issue_chunk(n + 2, ibuf);  // ibuf last read at compute(n-1)
    compute_chunk(cbuf);
    char* t0 = cbuf; cbuf = nbuf; nbuf = ibuf; ibuf = t0;
  }
  asm volatile("s_waitcnt vmcnt(0)" ::: "memory");
  __builtin_amdgcn_s_barrier();
  compute_chunk(cbuf);

  // ---- epilogue: each wave finishes its own 16 rows (all 64 cols) ----
  float cc[4];
#pragma unroll
  for (int ct = 0; ct < 4; ++ct) cc[ct] = cfin[ct * 16 + l15];

  const float scale = 2.0f / (float)DIM;
  float ce_part = 0.f;
  float ac_part = 0.f;
  int rowbase = row0 + wv * 16;

#pragma unroll
  for (int r = 0; r < 4; ++r) {
    int row = rowbase + g * 4 + r;
    int wy = row >> 9;           // true class = row / N_QUERY

    float s0 = acc[0][r] * scale - cc[0];
    float s1 = acc[1][r] * scale - cc[1];
    float s2 = acc[2][r] * scale - cc[2];
    float s3 = acc[3][r] * scale - cc[3];

    float mx = fmaxf(fmaxf(s0, s1), fmaxf(s2, s3));
#pragma unroll
    for (int off = 1; off < 16; off <<= 1) mx = fmaxf(mx, __shfl_xor(mx, off));

    float e = __expf(s0 - mx) + __expf(s1 - mx) + __expf(s2 - mx) + __expf(s3 - mx);
#pragma unroll
    for (int off = 1; off < 16; off <<= 1) e += __shfl_xor(e, off);
    float lse = mx + __logf(e);

    size_t ob = (size_t)row * N_WAY + l15;
    out[ob]      = s0 - lse;
    out[ob + 16] = s1 - lse;
    out[ob + 32] = s2 - lse;
    out[ob + 48] = s3 - lse;

    // CE: -log_p[row, wy] = lse - s_wy ; col ct*16+l15 == wy
    if (l15 == (wy & 15)) {
      int ct = wy >> 4;
      float sw = (ct == 0) ? s0 : (ct == 1) ? s1 : (ct == 2) ? s2 : s3;
      ce_part += lse - sw;
    }

    // argmax with first-occurrence tie-break
    float bv = s0; int bi = l15;
    if (s1 > bv) { bv = s1; bi = l15 + 16; }
    if (s2 > bv) { bv = s2; bi = l15 + 32; }
    if (s3 > bv) { bv = s3; bi = l15 + 48; }
#pragma unroll
    for (int off = 1; off < 16; off <<= 1) {
      float ov = __shfl_xor(bv, off);
      int oi = __shfl_xor(bi, off);
      if (ov > bv || (ov == bv && oi < bi)) { bv = ov; bi = oi; }
    }
    if (l15 == 0) ac_part += (bi == wy) ? 1.0f : 0.0f;
  }

  // block-level scalar reduce, one atomic pair per block
#pragma unroll
  for (int off = 1; off < 64; off <<= 1) {
    ce_part += __shfl_xor(ce_part, off);
    ac_part += __shfl_xor(ac_part, off);
  }
  if (lane == 0) { bred[wv][0] = ce_part; bred[wv][1] = ac_part; }
  __syncthreads();
  if (tid == 0) {
    float C = 0.f, A = 0.f;
#pragma unroll
    for (int j = 0; j < 8; ++j) { C += bred[j][0]; A += bred[j][1]; }
    atomicAdd(&scalars[0], C * (1.0f / N_ROWS));
    atomicAdd(&scalars[1], A * (1.0f / N_ROWS));
  }
}

// ---------------------------------------------------------------------------
extern "C" void kernel_launch(void* const* d_in, const int* in_sizes, int n_in,
                              void* d_out, int out_size, void* d_ws, size_t ws_size,
                              hipStream_t stream) {
  const float* s_emb = (const float*)d_in[0];
  const float* q_emb = (const float*)d_in[1];
  float* out = (float*)d_out;
  char* ws = (char*)d_ws;

  short* proto_sw = (short*)ws;                                // 256 KB
  float* c_part = (float*)(ws + 256 * 1024);                   // 2 KB
  float* scalars = out + OUT_LOGP;

  hipLaunchKernelGGL(proto_part, dim3(512), dim3(256), 0, stream,
                     s_emb, proto_sw, c_part, scalars);
  hipLaunchKernelGGL(dist_kernel, dim3(N_ROWS / RB), dim3(512), 0, stream,
                     q_emb, proto_sw, c_part, out, scalars);
}